// Round 1
// baseline (76.282 us; speedup 1.0000x reference)
//
#include <hip/hip_runtime.h>

// LaughingHyenaModalFilter: out[d,0]=h0[d]; out[d,l]=Re(sum_k R[k,d]*p[k,d]^(l-1)), p=r e^{i theta}.
// K=32, D=1024, L=2048.
//
// Two-kernel structure:
//  1) prep_kernel: per (k,d) computes the block-uniform quantities {log2 r, theta/2pi,
//     Re/Im(p^256), Rre, Rim} and packs them into a contiguous 192-float row per d in
//     the workspace. (These were previously computed per-block and staged through LDS:
//     192 same-address ds_read_b32 per thread = a per-CU LDS pipe storm, plus extra
//     trans ops and a serial if(tid<32) section.)
//  2) modal_filter_kernel: one block per d, 256 threads, thread j owns l in
//     {j, j+256, ...} (coalesced stores). All per-(k,d) constants are read with
//     wave-uniform loads -> scalar cache/SGPRs: ZERO LDS, zero barriers.
//     Complex recurrence z_k *= q_k (q_k = p_k^256) with k-pairs packed into float2
//     so the main loop lowers to v_pk_fma_f32/v_pk_mul_f32 (dual-FP32 VOP3P).
//     __launch_bounds__(256,2) guarantees a 256-VGPR budget for the ~160-VGPR live
//     state (64 Z + 64 Q + accum/temps) so nothing spills to scratch.

#define KP 32
#define KP2 16
#define DD 1024
#define LL 2048
#define PREPW (6 * KP)          // 192 floats per d
#define INV_2PI 0x1.45f306p-3f  // 1/(2*pi)

typedef float v2f __attribute__((ext_vector_type(2)));

__global__ __launch_bounds__(256) void prep_kernel(
    const float* __restrict__ r, const float* __restrict__ theta,
    const float* __restrict__ Rre, const float* __restrict__ Rim,
    float* __restrict__ prep) {
  const int d = blockIdx.x * 256 + threadIdx.x;  // coalesced over d
  const int k = blockIdx.y;
  const float rv = r[k * DD + d];
  const float th = theta[k * DD + d];
  const float lr = __builtin_amdgcn_logf(rv);    // v_log_f32: log2(r)
  const float thr = th * INV_2PI;                // theta in revolutions
  const float qmag = __builtin_amdgcn_exp2f(256.0f * lr);   // r^256
  const float qang = __builtin_amdgcn_fractf(256.0f * thr); // frac of 256*theta rev
  float* w = prep + (size_t)d * PREPW;
  w[k]          = lr;
  w[KP + k]     = thr;
  w[2 * KP + k] = qmag * __builtin_amdgcn_cosf(qang);  // Re(p^256)
  w[3 * KP + k] = qmag * __builtin_amdgcn_sinf(qang);  // Im(p^256)
  w[4 * KP + k] = Rre[k * DD + d];
  w[5 * KP + k] = Rim[k * DD + d];
}

__global__ __launch_bounds__(256, 2) void modal_filter_kernel(
    const float* __restrict__ prep, const float* __restrict__ h0,
    float* __restrict__ out) {
  const int d = blockIdx.x;
  const int tid = threadIdx.x;
  // Block-uniform row: compiler sees uniform addresses -> s_load into SGPRs.
  const float* __restrict__ w = prep + (size_t)d * PREPW;

  // z_k = R_k * p_k^{t0}, t0 = tid-1 (tid 0's l=0 slot is h0). Packed 2 k's per reg.
  v2f ZRE[KP2], ZIM[KP2], QRE[KP2], QIM[KP2];
  const float t0 = (float)tid - 1.0f;
#pragma unroll
  for (int kk = 0; kk < KP2; ++kk) {
#pragma unroll
    for (int j = 0; j < 2; ++j) {
      const int k = 2 * kk + j;
      const float lr = w[k];                                // SGPR
      const float thr = w[KP + k];                          // SGPR
      const float mag = __builtin_amdgcn_exp2f(t0 * lr);    // r^t0
      const float ang = __builtin_amdgcn_fractf(t0 * thr);
      const float c = __builtin_amdgcn_cosf(ang);           // cos(2*pi*ang)
      const float s = __builtin_amdgcn_sinf(ang);
      const float wre = mag * c, wim = mag * s;             // p^t0
      const float Rr = w[4 * KP + k];                       // SGPR
      const float Ri = w[5 * KP + k];                       // SGPR
      ZRE[kk][j] = Rr * wre - Ri * wim;
      ZIM[kk][j] = Rr * wim + Ri * wre;
      QRE[kk][j] = w[2 * KP + k];
      QIM[kk][j] = w[3 * KP + k];
    }
  }

  float* outd = out + (size_t)d * LL;
  const float h0d = h0[d];

#pragma unroll
  for (int s = 0; s < 8; ++s) {
    // h contribution = sum_k Re(z_k); 4 packed accumulators to shorten dep chains.
    v2f a0 = {0.f, 0.f}, a1 = {0.f, 0.f}, a2 = {0.f, 0.f}, a3 = {0.f, 0.f};
#pragma unroll
    for (int kk = 0; kk < KP2; kk += 4) {
      a0 += ZRE[kk];
      a1 += ZRE[kk + 1];
      a2 += ZRE[kk + 2];
      a3 += ZRE[kk + 3];
    }
    const v2f aa = (a0 + a1) + (a2 + a3);
    const float acc = aa[0] + aa[1];
    const int l = tid + 256 * s;
    outd[l] = (l == 0) ? h0d : acc;  // coalesced across the wave
    if (s < 7) {
#pragma unroll
      for (int kk = 0; kk < KP2; ++kk) {
        const v2f nr = ZRE[kk] * QRE[kk] - ZIM[kk] * QIM[kk];  // v_pk_mul + v_pk_fma
        const v2f ni = ZRE[kk] * QIM[kk] + ZIM[kk] * QRE[kk];
        ZRE[kk] = nr;
        ZIM[kk] = ni;
      }
    }
  }
}

extern "C" void kernel_launch(void* const* d_in, const int* in_sizes, int n_in,
                              void* d_out, int out_size, void* d_ws, size_t ws_size,
                              hipStream_t stream) {
  const float* r     = (const float*)d_in[0];
  const float* theta = (const float*)d_in[1];
  const float* Rre   = (const float*)d_in[2];
  const float* Rim   = (const float*)d_in[3];
  const float* h0    = (const float*)d_in[4];
  float* out = (float*)d_out;
  float* prep = (float*)d_ws;  // needs 6*32*1024*4 B = 768 KB; ws is ~256 MB

  prep_kernel<<<dim3(DD / 256, KP), 256, 0, stream>>>(r, theta, Rre, Rim, prep);
  modal_filter_kernel<<<DD, 256, 0, stream>>>(prep, h0, out);
}

// Round 2
// 73.532 us; speedup vs baseline: 1.0374x; 1.0374x over previous
//
#include <hip/hip_runtime.h>

// LaughingHyenaModalFilter: out[d,0]=h0[d]; out[d,l]=Re(sum_k R[k,d]*p[k,d]^(l-1)), p=r e^{i theta}.
// K=32, D=1024, L=2048.
//
// Single kernel, one block per d, 256 threads. Thread j owns the 8 CONSECUTIVE
// outputs l in [8j, 8j+8): z_k initialized at t0 = 8j-1 via native exp2/fract/sin/cos
// (v_sin_f32 takes REVOLUTIONS -> theta pre-scaled by 1/2pi), then the recurrence is
// simply z_k *= p_k per step (p staged in LDS by tid<32; uniform broadcast reads).
// Results collected in a[8] and written as two global_store_dwordx4.
// k-pairs packed into float2 so the main loop lowers to v_pk_fma_f32/v_pk_mul_f32.
//
// NOTE (measured, rounds 0-1): this kernel is ~3-5 us by issue-cycle arithmetic and
// does not appear in the rocprof top-5; dur_us is dominated by the harness's 256 MiB
// workspace poison fill (~40 us @ 84% HBM peak) + per-iteration reset dispatches.
// Round-1's 2-kernel split cost exactly one launch (+1.9 us) with no kernel delta ->
// single launch is the correct structure.

#define KP 32
#define KP2 16
#define DD 1024
#define LL 2048
#define INV_2PI 0x1.45f306p-3f  // 1/(2*pi)

typedef float v2f __attribute__((ext_vector_type(2)));

__global__ __launch_bounds__(256, 2) void modal_filter_kernel(
    const float* __restrict__ r, const float* __restrict__ theta,
    const float* __restrict__ Rre, const float* __restrict__ Rim,
    const float* __restrict__ h0, float* __restrict__ out) {
  const int d = blockIdx.x;
  const int tid = threadIdx.x;

  __shared__ float s_lr[KP];   // log2(r)
  __shared__ float s_thr[KP];  // theta / (2*pi)
  __shared__ float s_pre[KP];  // Re(p)
  __shared__ float s_pim[KP];  // Im(p)
  __shared__ float s_Rre[KP];
  __shared__ float s_Rim[KP];

  if (tid < KP) {
    const float rv = r[tid * DD + d];
    const float th = theta[tid * DD + d];
    const float lr = __builtin_amdgcn_logf(rv);   // v_log_f32: log2
    const float thr = th * INV_2PI;               // theta in revolutions
    const float ang = __builtin_amdgcn_fractf(thr);
    s_lr[tid] = lr;
    s_thr[tid] = thr;
    s_pre[tid] = rv * __builtin_amdgcn_cosf(ang);
    s_pim[tid] = rv * __builtin_amdgcn_sinf(ang);
    s_Rre[tid] = Rre[tid * DD + d];
    s_Rim[tid] = Rim[tid * DD + d];
  }
  const float h0d = h0[d];  // uniform -> s_load, hoisted above the barrier
  __syncthreads();

  // z_k = R_k * p_k^{t0}, t0 = 8*tid - 1 (thread's first slot l=8*tid has h-index
  // l-1 = 8*tid-1; tid 0's l=0 slot is replaced by h0). Packed 2 k's per reg.
  v2f ZRE[KP2], ZIM[KP2], PRE[KP2], PIM[KP2];
  const float t0 = 8.0f * (float)tid - 1.0f;
#pragma unroll
  for (int kk = 0; kk < KP2; ++kk) {
#pragma unroll
    for (int j = 0; j < 2; ++j) {
      const int k = 2 * kk + j;
      const float mag = __builtin_amdgcn_exp2f(t0 * s_lr[k]);   // r^t0
      const float ang = __builtin_amdgcn_fractf(t0 * s_thr[k]);
      const float c = __builtin_amdgcn_cosf(ang);               // cos(2*pi*ang)
      const float s = __builtin_amdgcn_sinf(ang);
      const float wre = mag * c, wim = mag * s;                 // p^t0
      ZRE[kk][j] = s_Rre[k] * wre - s_Rim[k] * wim;
      ZIM[kk][j] = s_Rre[k] * wim + s_Rim[k] * wre;
      PRE[kk][j] = s_pre[k];
      PIM[kk][j] = s_pim[k];
    }
  }

  float a[8];
#pragma unroll
  for (int i = 0; i < 8; ++i) {
    // h contribution = sum_k Re(z_k); 4 packed accumulators to shorten dep chains.
    v2f a0 = {0.f, 0.f}, a1 = {0.f, 0.f}, a2 = {0.f, 0.f}, a3 = {0.f, 0.f};
#pragma unroll
    for (int kk = 0; kk < KP2; kk += 4) {
      a0 += ZRE[kk];
      a1 += ZRE[kk + 1];
      a2 += ZRE[kk + 2];
      a3 += ZRE[kk + 3];
    }
    const v2f aa = (a0 + a1) + (a2 + a3);
    a[i] = aa[0] + aa[1];
    if (i < 7) {
#pragma unroll
      for (int kk = 0; kk < KP2; ++kk) {
        const v2f nr = ZRE[kk] * PRE[kk] - ZIM[kk] * PIM[kk];  // v_pk_mul + v_pk_fma
        const v2f ni = ZRE[kk] * PIM[kk] + ZIM[kk] * PRE[kk];
        ZRE[kk] = nr;
        ZIM[kk] = ni;
      }
    }
  }
  if (tid == 0) a[0] = h0d;

  // Two 16B stores: thread j covers bytes [32j, 32j+32) of row d -> the wave's two
  // dwordx4 instructions jointly cover a contiguous 2 KB span.
  float4* o4 = reinterpret_cast<float4*>(out + (size_t)d * LL);
  o4[2 * tid]     = make_float4(a[0], a[1], a[2], a[3]);
  o4[2 * tid + 1] = make_float4(a[4], a[5], a[6], a[7]);
}

extern "C" void kernel_launch(void* const* d_in, const int* in_sizes, int n_in,
                              void* d_out, int out_size, void* d_ws, size_t ws_size,
                              hipStream_t stream) {
  const float* r     = (const float*)d_in[0];
  const float* theta = (const float*)d_in[1];
  const float* Rre   = (const float*)d_in[2];
  const float* Rim   = (const float*)d_in[3];
  const float* h0    = (const float*)d_in[4];
  float* out = (float*)d_out;

  modal_filter_kernel<<<DD, 256, 0, stream>>>(r, theta, Rre, Rim, h0, out);
}